// Round 9
// baseline (308.385 us; speedup 1.0000x reference)
//
#include <hip/hip_runtime.h>
#include <math.h>

// SPP: out = concat(x, mp5(x), mp9(x), mp13(x)) along channels.
// x: (32, 512, 32, 32) fp32 -> out: (32, 2048, 32, 32) fp32.
//
// Round-8 = R7's verified compute core (single-barrier fan-out: all 3
// levels direct from halo-staged input via incremental column maxes,
// horizontal windows in registers via __shfl, nt on both streams) +
// PERSISTENT 8-PLANE BLOCKS with software pipelining:
//   - grid 2048 (8 blocks/CU exactly); each block loops over 8 planes
//   - plane i+1's global load ISSUES before plane i's barrier -> HBM
//     read latency hides under plane i's compute/stores; read stream
//     is continuous instead of one exposed 4KB load per micro-block
//   - amortizes 16384x {launch, kernarg loads, end-of-kernel release
//     fence} down to 2048x
//   - double-buffered LDS planes -> ONE barrier per plane. Safety: iter
//     i's barrier separates iter i-1's reads of buf[(i+1)&1] from iter
//     i+1's staging of it (a wave stages i+1 only after passing barrier
//     i, which requires ALL waves to have finished iter i-1's reads).
//
// LDS: 2 * 44 * 36 * 4 = 12,672 B; __launch_bounds__(256,8) -> 8
// blocks/CU. STRF=36: b128 16B-aligned, bank-uniform (8 words/bank).

constexpr int STRF = 36;             // LDS row stride in floats
constexpr int HROWS = 44;            // 6 halo + 32 + 6 halo
constexpr int PPB = 8;               // planes per block

typedef float float4n __attribute__((ext_vector_type(4)));  // native vec4

__device__ __forceinline__ float4 nt_load4(const float4* p) {
  float4n w = __builtin_nontemporal_load((const float4n*)p);
  return make_float4(w.x, w.y, w.z, w.w);
}
__device__ __forceinline__ void nt_store4(float4 v, float4* p) {
  float4n w = {v.x, v.y, v.z, v.w};
  __builtin_nontemporal_store(w, (float4n*)p);
}

__device__ __forceinline__ float fmax3(float a, float b, float c) {
  return fmaxf(fmaxf(a, b), c);     // clang fuses to v_max3_f32
}
__device__ __forceinline__ float4 vmax(float4 a, float4 b) {
  return make_float4(fmaxf(a.x, b.x), fmaxf(a.y, b.y), fmaxf(a.z, b.z),
                     fmaxf(a.w, b.w));
}

__global__ __launch_bounds__(256, 8) void spp_kernel(
    const float* __restrict__ x, float* __restrict__ out) {
  __shared__ __align__(16) float Abuf[2][HROWS * STRF];  // 12,672 B

  const int t = threadIdx.x;
  const int r = t >> 3;                // row 0..31
  const int c0 = (t & 7) * 4;          // col base 0..28
  const int pbase = blockIdx.x * PPB;  // 8 consecutive planes, same n
  const int n = pbase >> 9;            // (8 | 512 -> never crosses n)
  const int cbase = pbase & 511;

  const float4* __restrict__ xin = (const float4*)x + (size_t)pbase * 256;
  float4* __restrict__ outn = (float4*)out + (size_t)n * 2048 * 256;

  // Edge validity of lane-neighbor shuffles (lane +/-1 == cols +/-4).
  const bool gL1 = (c0 >= 4), gL2 = (c0 >= 8);
  const bool gR1 = (c0 <= 24), gR2 = (c0 <= 20);
  const float NI = -INFINITY;

  float4 v = nt_load4(&xin[t]);        // prefetch plane 0

  #pragma unroll
  for (int i = 0; i < PPB; ++i) {
    float* const A = Abuf[i & 1];
    float4* const oid = outn + (size_t)(cbase + i) * 256;

    // ---- prefetch next plane EARLY (hides under this plane's work) ----
    float4 vn = v;
    if (i < PPB - 1) vn = nt_load4(&xin[(i + 1) * 256 + t]);

    // ---- stage current plane (halo rows -6..37, clamped) + identity ----
    *(float4*)(&A[(r + 6) * STRF + c0]) = v;
    if (r == 0) {
      #pragma unroll
      for (int d = 0; d < 6; ++d) *(float4*)(&A[d * STRF + c0]) = v;
    } else if (r == 31) {
      #pragma unroll
      for (int d = 0; d < 6; ++d) *(float4*)(&A[(38 + d) * STRF + c0]) = v;
    }
    nt_store4(v, &oid[t]);
    __syncthreads();                   // the only barrier per plane

    // ---- vertical pass: incremental column maxes over 13 halo rows ----
    const float* base = &A[r * STRF + c0];  // physical r == logical r-6
    const float4 u4 = *(const float4*)(base + 4 * STRF);
    const float4 u5 = *(const float4*)(base + 5 * STRF);
    const float4 u6 = *(const float4*)(base + 6 * STRF);
    const float4 u7 = *(const float4*)(base + 7 * STRF);
    const float4 u8 = *(const float4*)(base + 8 * STRF);
    const float4 cm5 = vmax(vmax(vmax(u4, u5), vmax(u6, u7)), u8);
    const float4 u2 = *(const float4*)(base + 2 * STRF);
    const float4 u3 = *(const float4*)(base + 3 * STRF);
    const float4 u9 = *(const float4*)(base + 9 * STRF);
    const float4 u10 = *(const float4*)(base + 10 * STRF);
    const float4 cm9 = vmax(cm5, vmax(vmax(u2, u3), vmax(u9, u10)));
    const float4 u0 = *(const float4*)(base + 0 * STRF);
    const float4 u1 = *(const float4*)(base + 1 * STRF);
    const float4 u11 = *(const float4*)(base + 11 * STRF);
    const float4 u12 = *(const float4*)(base + 12 * STRF);
    const float4 cm13 = vmax(cm9, vmax(vmax(u0, u1), vmax(u11, u12)));

    // ---- level 1: mp5 (window +/-2) ----
    {
      float a2 = __shfl_up(cm5.z, 1);  a2 = gL1 ? a2 : NI;   // col c0-2
      float a3 = __shfl_up(cm5.w, 1);  a3 = gL1 ? a3 : NI;   // col c0-1
      float b0 = __shfl_down(cm5.x, 1); b0 = gR1 ? b0 : NI;  // col c0+4
      float b1 = __shfl_down(cm5.y, 1); b1 = gR1 ? b1 : NI;  // col c0+5
      float4 m;
      m.x = fmaxf(fmax3(a2, a3, cm5.x), fmaxf(cm5.y, cm5.z));
      m.y = fmaxf(fmax3(a3, cm5.x, cm5.y), fmaxf(cm5.z, cm5.w));
      m.z = fmaxf(fmax3(cm5.x, cm5.y, cm5.z), fmaxf(cm5.w, b0));
      m.w = fmaxf(fmax3(cm5.y, cm5.z, cm5.w), fmaxf(b0, b1));
      nt_store4(m, &oid[131072 + t]);  // +512 channels
    }

    // ---- level 2: mp9 (window +/-4) ----
    {
      float L0 = __shfl_up(cm9.x, 1), L1 = __shfl_up(cm9.y, 1);
      float L2 = __shfl_up(cm9.z, 1), L3 = __shfl_up(cm9.w, 1);
      float R0 = __shfl_down(cm9.x, 1), R1 = __shfl_down(cm9.y, 1);
      float R2 = __shfl_down(cm9.z, 1), R3 = __shfl_down(cm9.w, 1);
      L0 = gL1 ? L0 : NI; L1 = gL1 ? L1 : NI;
      L2 = gL1 ? L2 : NI; L3 = gL1 ? L3 : NI;
      R0 = gR1 ? R0 : NI; R1 = gR1 ? R1 : NI;
      R2 = gR1 ? R2 : NI; R3 = gR1 ? R3 : NI;
      const float core = fmaxf(fmaxf(cm9.x, cm9.y), fmaxf(cm9.z, cm9.w));
      const float S3 = L3, S2 = fmaxf(L2, S3), S1 = fmaxf(L1, S2),
                  S0 = fmaxf(L0, S1);
      const float P0 = R0, P1 = fmaxf(R1, P0), P2 = fmaxf(R2, P1),
                  P3 = fmaxf(R3, P2);
      float4 m;
      m.x = fmax3(S0, core, P0);
      m.y = fmax3(S1, core, P1);
      m.z = fmax3(S2, core, P2);
      m.w = fmax3(S3, core, P3);
      nt_store4(m, &oid[262144 + t]);
    }

    // ---- level 3: mp13 (window +/-6) ----
    {
      float L0 = __shfl_up(cm13.x, 1), L1 = __shfl_up(cm13.y, 1);
      float L2 = __shfl_up(cm13.z, 1), L3 = __shfl_up(cm13.w, 1);
      float LL2 = __shfl_up(cm13.z, 2), LL3 = __shfl_up(cm13.w, 2);
      float R0 = __shfl_down(cm13.x, 1), R1 = __shfl_down(cm13.y, 1);
      float R2 = __shfl_down(cm13.z, 1), R3 = __shfl_down(cm13.w, 1);
      float RR0 = __shfl_down(cm13.x, 2), RR1 = __shfl_down(cm13.y, 2);
      L0 = gL1 ? L0 : NI; L1 = gL1 ? L1 : NI;
      L2 = gL1 ? L2 : NI; L3 = gL1 ? L3 : NI;
      LL2 = gL2 ? LL2 : NI; LL3 = gL2 ? LL3 : NI;    // cols c0-6, c0-5
      R0 = gR1 ? R0 : NI; R1 = gR1 ? R1 : NI;
      R2 = gR1 ? R2 : NI; R3 = gR1 ? R3 : NI;
      RR0 = gR2 ? RR0 : NI; RR1 = gR2 ? RR1 : NI;    // cols c0+8, c0+9
      const float core = fmaxf(fmaxf(cm13.x, cm13.y), fmaxf(cm13.z, cm13.w));
      const float S5 = L3, S4 = fmaxf(L2, S5), S3 = fmaxf(L1, S4),
                  S2 = fmaxf(L0, S3), S1 = fmaxf(LL3, S2),
                  S0 = fmaxf(LL2, S1);
      const float P0 = R0, P1 = fmaxf(R1, P0), P2 = fmaxf(R2, P1),
                  P3 = fmaxf(R3, P2), P4 = fmaxf(RR0, P3),
                  P5 = fmaxf(RR1, P4);
      float4 m;
      m.x = fmax3(S0, core, P2);   // cols c0-6 .. c0+6
      m.y = fmax3(S1, core, P3);   // cols c0-5 .. c0+7
      m.z = fmax3(S2, core, P4);   // cols c0-4 .. c0+8
      m.w = fmax3(S3, core, P5);   // cols c0-3 .. c0+9
      nt_store4(m, &oid[393216 + t]);
    }

    v = vn;  // hand the prefetched plane to the next iteration
  }
}

extern "C" void kernel_launch(void* const* d_in, const int* in_sizes, int n_in,
                              void* d_out, int out_size, void* d_ws,
                              size_t ws_size, hipStream_t stream) {
  const float* x = (const float*)d_in[0];
  float* out = (float*)d_out;
  // 16384 planes / 8 planes per block = 2048 blocks = 8 blocks/CU exactly
  spp_kernel<<<2048, 256, 0, stream>>>(x, out);
}

// Round 10
// 297.363 us; speedup vs baseline: 1.0371x; 1.0371x over previous
//
#include <hip/hip_runtime.h>
#include <math.h>

// SPP: out = concat(x, mp5(x), mp9(x), mp13(x)) along channels.
// x: (32, 512, 32, 32) fp32 -> out: (32, 2048, 32, 32) fp32.
//
// FINAL (= round-8 measured best, 298.06 us): single-barrier fan-out
// with nontemporal on both streams. One block per (n,c) plane.
//
// Why this shape won (9-round evidence):
//  - All 3 levels computed DIRECTLY from the halo-staged input plane:
//    mp9 = 9-tap, mp13 = 13-tap separable max; incremental column maxes
//    cm5 -> cm9 -> cm13 cost 13 ds_read_b128 total, ONE __syncthreads.
//  - Horizontal windows entirely in registers: neighbor column-maxes via
//    __shfl (lane +/-1 == cols +/-4) + prefix/suffix max chains.
//  - nt loads/stores: all 335 MB of traffic is stream-once; bypassing
//    L2/L3 retention gave the only real memory-path win (-6 us).
//  - Micro-blocks beat coarse blocks: every multi-plane-per-block
//    variant (2/4/8 planes) cost +10..17 us (longer serial chains);
//    schedule/occupancy/barrier changes were all within +/-1.5 us.
// LDS 6336 B, 32 waves/CU; STRF=36 keeps b128 16B-aligned and
// bank-uniform (8 words/bank per wave instruction).

constexpr int STRF = 36;             // LDS row stride in floats
constexpr int HROWS = 44;            // 6 halo + 32 + 6 halo

typedef float float4n __attribute__((ext_vector_type(4)));  // native vec4

__device__ __forceinline__ float4 nt_load4(const float4* p) {
  float4n w = __builtin_nontemporal_load((const float4n*)p);
  return make_float4(w.x, w.y, w.z, w.w);
}
__device__ __forceinline__ void nt_store4(float4 v, float4* p) {
  float4n w = {v.x, v.y, v.z, v.w};
  __builtin_nontemporal_store(w, (float4n*)p);
}

__device__ __forceinline__ float fmax3(float a, float b, float c) {
  return fmaxf(fmaxf(a, b), c);     // clang fuses to v_max3_f32
}
__device__ __forceinline__ float4 vmax(float4 a, float4 b) {
  return make_float4(fmaxf(a.x, b.x), fmaxf(a.y, b.y), fmaxf(a.z, b.z),
                     fmaxf(a.w, b.w));
}

__global__ __launch_bounds__(256, 8) void spp_kernel(
    const float* __restrict__ x, float* __restrict__ out) {
  __shared__ __align__(16) float A[HROWS * STRF];  // 6336 B

  const int t = threadIdx.x;
  const int plane = blockIdx.x;        // n*512 + c
  const int n = plane >> 9;
  const int c = plane & 511;
  const int r = t >> 3;                // row 0..31
  const int c0 = (t & 7) * 4;          // col base 0..28

  const float4* __restrict__ xin = (const float4*)x + (size_t)plane * 256;
  float4* __restrict__ oid = (float4*)out + ((size_t)n * 2048 + c) * 256;

  // ---- nt load, nt identity store, halo-stage ----
  float4 v = nt_load4(&xin[t]);
  nt_store4(v, &oid[t]);
  *(float4*)(&A[(r + 6) * STRF + c0]) = v;   // physical row = logical + 6
  if (r == 0) {
    #pragma unroll
    for (int d = 0; d < 6; ++d) *(float4*)(&A[d * STRF + c0]) = v;
  } else if (r == 31) {
    #pragma unroll
    for (int d = 0; d < 6; ++d) *(float4*)(&A[(38 + d) * STRF + c0]) = v;
  }
  __syncthreads();                     // the ONLY barrier

  // ---- vertical pass: incremental column maxes over 13 halo rows ----
  const float* base = &A[r * STRF + c0];  // physical r == logical r-6
  const float4 u4 = *(const float4*)(base + 4 * STRF);
  const float4 u5 = *(const float4*)(base + 5 * STRF);
  const float4 u6 = *(const float4*)(base + 6 * STRF);
  const float4 u7 = *(const float4*)(base + 7 * STRF);
  const float4 u8 = *(const float4*)(base + 8 * STRF);
  const float4 cm5 = vmax(vmax(vmax(u4, u5), vmax(u6, u7)), u8);
  const float4 u2 = *(const float4*)(base + 2 * STRF);
  const float4 u3 = *(const float4*)(base + 3 * STRF);
  const float4 u9 = *(const float4*)(base + 9 * STRF);
  const float4 u10 = *(const float4*)(base + 10 * STRF);
  const float4 cm9 = vmax(cm5, vmax(vmax(u2, u3), vmax(u9, u10)));
  const float4 u0 = *(const float4*)(base + 0 * STRF);
  const float4 u1 = *(const float4*)(base + 1 * STRF);
  const float4 u11 = *(const float4*)(base + 11 * STRF);
  const float4 u12 = *(const float4*)(base + 12 * STRF);
  const float4 cm13 = vmax(cm9, vmax(vmax(u0, u1), vmax(u11, u12)));

  // Edge validity of lane-neighbor shuffles (lane +/-1 == cols +/-4).
  const bool gL1 = (c0 >= 4), gL2 = (c0 >= 8);
  const bool gR1 = (c0 <= 24), gR2 = (c0 <= 20);
  const float NI = -INFINITY;

  // ---- level 1: mp5 (window +/-2) ----
  {
    float a2 = __shfl_up(cm5.z, 1);  a2 = gL1 ? a2 : NI;   // col c0-2
    float a3 = __shfl_up(cm5.w, 1);  a3 = gL1 ? a3 : NI;   // col c0-1
    float b0 = __shfl_down(cm5.x, 1); b0 = gR1 ? b0 : NI;  // col c0+4
    float b1 = __shfl_down(cm5.y, 1); b1 = gR1 ? b1 : NI;  // col c0+5
    float4 m;
    m.x = fmaxf(fmax3(a2, a3, cm5.x), fmaxf(cm5.y, cm5.z));
    m.y = fmaxf(fmax3(a3, cm5.x, cm5.y), fmaxf(cm5.z, cm5.w));
    m.z = fmaxf(fmax3(cm5.x, cm5.y, cm5.z), fmaxf(cm5.w, b0));
    m.w = fmaxf(fmax3(cm5.y, cm5.z, cm5.w), fmaxf(b0, b1));
    nt_store4(m, &oid[131072 + t]);  // +512 channels
  }

  // ---- level 2: mp9 (window +/-4) ----
  {
    float L0 = __shfl_up(cm9.x, 1), L1 = __shfl_up(cm9.y, 1);
    float L2 = __shfl_up(cm9.z, 1), L3 = __shfl_up(cm9.w, 1);
    float R0 = __shfl_down(cm9.x, 1), R1 = __shfl_down(cm9.y, 1);
    float R2 = __shfl_down(cm9.z, 1), R3 = __shfl_down(cm9.w, 1);
    L0 = gL1 ? L0 : NI; L1 = gL1 ? L1 : NI;
    L2 = gL1 ? L2 : NI; L3 = gL1 ? L3 : NI;
    R0 = gR1 ? R0 : NI; R1 = gR1 ? R1 : NI;
    R2 = gR1 ? R2 : NI; R3 = gR1 ? R3 : NI;
    const float core = fmaxf(fmaxf(cm9.x, cm9.y), fmaxf(cm9.z, cm9.w));
    const float S3 = L3, S2 = fmaxf(L2, S3), S1 = fmaxf(L1, S2),
                S0 = fmaxf(L0, S1);
    const float P0 = R0, P1 = fmaxf(R1, P0), P2 = fmaxf(R2, P1),
                P3 = fmaxf(R3, P2);
    float4 m;
    m.x = fmax3(S0, core, P0);
    m.y = fmax3(S1, core, P1);
    m.z = fmax3(S2, core, P2);
    m.w = fmax3(S3, core, P3);
    nt_store4(m, &oid[262144 + t]);
  }

  // ---- level 3: mp13 (window +/-6) ----
  {
    float L0 = __shfl_up(cm13.x, 1), L1 = __shfl_up(cm13.y, 1);
    float L2 = __shfl_up(cm13.z, 1), L3 = __shfl_up(cm13.w, 1);
    float LL2 = __shfl_up(cm13.z, 2), LL3 = __shfl_up(cm13.w, 2);
    float R0 = __shfl_down(cm13.x, 1), R1 = __shfl_down(cm13.y, 1);
    float R2 = __shfl_down(cm13.z, 1), R3 = __shfl_down(cm13.w, 1);
    float RR0 = __shfl_down(cm13.x, 2), RR1 = __shfl_down(cm13.y, 2);
    L0 = gL1 ? L0 : NI; L1 = gL1 ? L1 : NI;
    L2 = gL1 ? L2 : NI; L3 = gL1 ? L3 : NI;
    LL2 = gL2 ? LL2 : NI; LL3 = gL2 ? LL3 : NI;    // cols c0-6, c0-5
    R0 = gR1 ? R0 : NI; R1 = gR1 ? R1 : NI;
    R2 = gR1 ? R2 : NI; R3 = gR1 ? R3 : NI;
    RR0 = gR2 ? RR0 : NI; RR1 = gR2 ? RR1 : NI;    // cols c0+8, c0+9
    const float core = fmaxf(fmaxf(cm13.x, cm13.y), fmaxf(cm13.z, cm13.w));
    const float S5 = L3, S4 = fmaxf(L2, S5), S3 = fmaxf(L1, S4),
                S2 = fmaxf(L0, S3), S1 = fmaxf(LL3, S2),
                S0 = fmaxf(LL2, S1);
    const float P0 = R0, P1 = fmaxf(R1, P0), P2 = fmaxf(R2, P1),
                P3 = fmaxf(R3, P2), P4 = fmaxf(RR0, P3),
                P5 = fmaxf(RR1, P4);
    float4 m;
    m.x = fmax3(S0, core, P2);   // cols c0-6 .. c0+6
    m.y = fmax3(S1, core, P3);   // cols c0-5 .. c0+7
    m.z = fmax3(S2, core, P4);   // cols c0-4 .. c0+8
    m.w = fmax3(S3, core, P5);   // cols c0-3 .. c0+9
    nt_store4(m, &oid[393216 + t]);
  }
}

extern "C" void kernel_launch(void* const* d_in, const int* in_sizes, int n_in,
                              void* d_out, int out_size, void* d_ws,
                              size_t ws_size, hipStream_t stream) {
  const float* x = (const float*)d_in[0];
  float* out = (float*)d_out;
  spp_kernel<<<32 * 512, 256, 0, stream>>>(x, out);  // 1 block per plane
}